// Round 13
// baseline (282.315 us; speedup 1.0000x reference)
//
#include <hip/hip_runtime.h>

#define KCODES 16384
#define CDIM   32
#define NROWS  8192
#define KSPLIT 8                  // chunks (blockIdx.y)
#define CHUNK  (KCODES/KSPLIT)    // 2048
#define WCODES (CHUNK/4)          // 512 codes per wave
#define NT     (WCODES/16)        // 32 MFMA code-tiles per wave
#define NRG    (NROWS/32)         // 256 rowgroups
#define MARGIN 6.0f               // covers f16 mfma err (~0.8) + 2x 11-bit tag noise (~1.6 each)

typedef _Float16 half8 __attribute__((ext_vector_type(8)));
typedef float    floatx4 __attribute__((ext_vector_type(4)));

// workspace layout (float indices)
#define WS_MSE   0
#define WS_PLP   1
#define WS_GCNT  2                       // int: finalize gate
#define WS_AVGP  16                      // [16384]
#define WS_ENORM (16 + KCODES)           // [16384] fp32, exact
#define WS_ZNORM (16 + 2*KCODES)         // [8192]
#define WS_PART  (16 + 2*KCODES + NROWS) // float4[KSPLIT][NROWS]
#define WS_CNT   (WS_PART + 4*KSPLIT*NROWS)  // 256 ints: per-rowgroup gates
#define WS_E16   (WS_CNT + 256)              // f16[16384][32]
#define WS_Z16   (WS_E16 + KCODES*16)        // f16[8192][32]

// output layout (floats): z_q [0, N*C), loss [N*C], idx [N*C+1, ...)
#define OUT_LOSS (NROWS*CDIM)
#define OUT_IDX  (NROWS*CDIM + 1)

#define AGLOAD(p) __hip_atomic_load((p), __ATOMIC_RELAXED, __HIP_MEMORY_SCOPE_AGENT)

// ---------------------------------------------------------------------------
// prep: blocks [0,64): e-rows (enorm + f16 + zero avg_probs);
//       blocks [64,96): z-rows (znorm + f16); block 64 zeroes scalars+counters.
// ---------------------------------------------------------------------------
__global__ __launch_bounds__(256) void prep_kernel(const float* __restrict__ z,
                                                   const float* __restrict__ emb,
                                                   float* __restrict__ ws) {
  const int tid = threadIdx.x;
  if (blockIdx.x < 64) {
    int k = blockIdx.x * 256 + tid;
    const float4* p = (const float4*)(emb + (size_t)k * CDIM);
    _Float16* e16 = (_Float16*)(ws + WS_E16);
    float s = 0.f;
    half8 h[4];
#pragma unroll
    for (int i = 0; i < 8; ++i) {
      float4 v = p[i];
      s += v.x*v.x + v.y*v.y + v.z*v.z + v.w*v.w;
      h[i>>1][(i&1)*4+0] = (_Float16)v.x;
      h[i>>1][(i&1)*4+1] = (_Float16)v.y;
      h[i>>1][(i&1)*4+2] = (_Float16)v.z;
      h[i>>1][(i&1)*4+3] = (_Float16)v.w;
    }
    ws[WS_ENORM + k] = s;
    ws[WS_AVGP + k]  = 0.f;
    half8* dst = (half8*)(e16 + (size_t)k*32);
#pragma unroll
    for (int i = 0; i < 4; ++i) dst[i] = h[i];
  } else {
    int b = blockIdx.x - 64;
    int n = b*256 + tid;
    if (b == 0) {
      ((int*)ws)[WS_CNT + tid] = 0;         // rowgroup gates
      if (tid < 16) ws[tid] = 0.f;          // MSE, PLP, GCNT, spare
    }
    _Float16* z16 = (_Float16*)(ws + WS_Z16);
    float s = 0.f;
    half8 h[4];
#pragma unroll
    for (int c = 0; c < CDIM; ++c) {
      float v = z[(size_t)b*8192 + c*256 + tid];
      s = fmaf(v, v, s);
      h[c>>3][c&7] = (_Float16)v;
    }
    ws[WS_ZNORM + n] = s;
    half8* dst = (half8*)(z16 + (size_t)n*32);
#pragma unroll
    for (int i = 0; i < 4; ++i) dst[i] = h[i];
  }
}

// ---------------------------------------------------------------------------
// gemm_pass (+fused combine/zq/finalize): block = (32 rows, chunk of 2048).
// Main loop: software-pipelined — tile t's MFMAs issue BEFORE tile t-1's
// epilogue (pack/med3/max overlap MFMA latency); 2-deep B prefetch via
// pointer increments (no per-tile 64-bit addr math). Tags: low 11 mantissa
// bits = within-chunk code; lp <= 0 always, so larger tag = more negative =
// ties resolve to the smaller code under fmax automatically.
// Tail: 8th-arriving chunk block per rowgroup does combine+zq (threadfence +
// agent atomic loads for cross-XCD part visibility); 256th rowgroup block
// does finalize. 2 dispatches total (R12's 4-dispatch tail was ~84 us).
// ---------------------------------------------------------------------------
__global__ __launch_bounds__(256) void gemm_pass(const float* __restrict__ z,
                                                 const float* __restrict__ emb,
                                                 float* __restrict__ ws,
                                                 float* __restrict__ out) {
  __shared__ float2 wdump[4][32];
  __shared__ float  red[256];
  __shared__ int    flag_s;

  const int tid  = threadIdx.x;
  const int wv   = tid >> 6;
  const int lane = tid & 63;
  const int nn   = lane & 15;
  const int quad = lane >> 4;
  const int n0   = blockIdx.x * 32;
  const int kb   = blockIdx.y * CHUNK + wv * WCODES;

  const half8* z16v  = (const half8*)(ws + WS_Z16);
  const float* enorm = ws + WS_ENORM;
  const float* znorm = ws + WS_ZNORM;
  float4* part = (float4*)(ws + WS_PART);

  half8 a0 = z16v[(size_t)(n0 + nn)*4 + quad];
  half8 a1 = z16v[(size_t)(n0 + 16 + nn)*4 + quad];

  float nzn2[8];
#pragma unroll
  for (int i = 0; i < 8; ++i)
    nzn2[i] = -0.5f * znorm[n0 + (i>>2)*16 + quad*4 + (i&3)];

  float t1l[8], t2l[8];
#pragma unroll
  for (int i = 0; i < 8; ++i) { t1l[i] = -3.0e38f; t2l[i] = -3.0e38f; }

  const half8* pb = (const half8*)(ws + WS_E16) + (size_t)(kb + nn)*4 + quad;
  const float* pe = enorm + kb + nn;
  const int tagb = wv*WCODES + nn;      // within-chunk code of tile 0

  // pipeline preamble: tiles 0,1 loaded; tile 0 MFMA issued
  half8 bB = pb[0];   float eB = pe[0];
  half8 bC = pb[64];  float eC = pe[16];
  floatx4 dp0, dp1;
  {
    float eh = 0.5f * eB;
    floatx4 c0, c1;
#pragma unroll
    for (int i = 0; i < 4; ++i) { c0[i] = nzn2[i] - eh; c1[i] = nzn2[i+4] - eh; }
    dp0 = __builtin_amdgcn_mfma_f32_16x16x32_f16(a0, bB, c0, 0, 0, 0);
    dp1 = __builtin_amdgcn_mfma_f32_16x16x32_f16(a1, bB, c1, 0, 0, 0);
  }
  bB = bC; eB = eC;
  bC = pb[128]; eC = pe[32];

  for (int t = 1; t < NT; ++t) {
    const int tp = (t + 2 < NT) ? t + 2 : NT - 1;
    half8 bN = pb[(size_t)64*tp];
    float eN = pe[16*tp];

    float eh = 0.5f * eB;
    floatx4 c0, c1;
#pragma unroll
    for (int i = 0; i < 4; ++i) { c0[i] = nzn2[i] - eh; c1[i] = nzn2[i+4] - eh; }
    floatx4 dn0 = __builtin_amdgcn_mfma_f32_16x16x32_f16(a0, bB, c0, 0, 0, 0);
    floatx4 dn1 = __builtin_amdgcn_mfma_f32_16x16x32_f16(a1, bB, c1, 0, 0, 0);

    const int tg = tagb + 16*(t-1);     // epilogue for tile t-1 overlaps MFMAs
#pragma unroll
    for (int i = 0; i < 8; ++i) {
      float lp = (i < 4) ? dp0[i & 3] : dp1[i & 3];
      float v  = __int_as_float((__float_as_int(lp) & 0xFFFFF800) | tg);
      t2l[i] = __builtin_amdgcn_fmed3f(v, t1l[i], t2l[i]);
      t1l[i] = fmaxf(t1l[i], v);
    }
    dp0 = dn0; dp1 = dn1; bB = bC; eB = eC; bC = bN; eC = eN;
  }
  {
    const int tg = tagb + 16*(NT-1);
#pragma unroll
    for (int i = 0; i < 8; ++i) {
      float lp = (i < 4) ? dp0[i & 3] : dp1[i & 3];
      float v  = __int_as_float((__float_as_int(lp) & 0xFFFFF800) | tg);
      t2l[i] = __builtin_amdgcn_fmed3f(v, t1l[i], t2l[i]);
      t1l[i] = fmaxf(t1l[i], v);
    }
  }

  // butterfly top-2 merge across the 16 nn-lanes
#pragma unroll
  for (int i = 0; i < 8; ++i) {
    float v1 = t1l[i], v2 = t2l[i];
#pragma unroll
    for (int m = 1; m < 16; m <<= 1) {
      float o1 = __shfl_xor(v1, m);
      float o2 = __shfl_xor(v2, m);
      float mn = fminf(v1, o1);
      v1 = fmaxf(v1, o1);
      v2 = fmaxf(mn, fmaxf(v2, o2));
    }
    if (nn == 0) wdump[wv][(i>>2)*16 + quad*4 + (i&3)] = make_float2(v1, v2);
  }
  __syncthreads();

  if (tid < 32) {   // merge 4 waves per row, unpack, write part
    float v1 = -3.0e38f, v2 = -3.0e38f;
#pragma unroll
    for (int w = 0; w < 4; ++w) {
      float2 p = wdump[w][tid];
      float mn = fminf(v1, p.x);
      v1 = fmaxf(v1, p.x);
      v2 = fmaxf(mn, fmaxf(v2, p.y));
    }
    int b1 = __float_as_int(v1), b2 = __float_as_int(v2);
    int c1i = blockIdx.y*CHUNK + (b1 & 0x7FF);
    int c2i = blockIdx.y*CHUNK + (b2 & 0x7FF);
    float l1 = 200.f * __int_as_float(b1 & 0xFFFFF800);
    float l2 = 200.f * __int_as_float(b2 & 0xFFFFF800);
    part[(size_t)blockIdx.y*NROWS + n0 + tid] =
        make_float4(l1, __int_as_float(c1i), l2, __int_as_float(c2i));
  }

  // ---- gate 1: last chunk block of this rowgroup does combine+zq ----
  __threadfence();
  __syncthreads();
  if (tid == 0)
    flag_s = (atomicAdd((int*)ws + WS_CNT + blockIdx.x, 1) == KSPLIT - 1);
  __syncthreads();
  if (!flag_s) return;
  __threadfence();

  if (tid < 32) {
    int n = n0 + tid;
    float l[16]; int c[16];
#pragma unroll
    for (int ch = 0; ch < KSPLIT; ++ch) {
      const float* pp = (const float*)&part[(size_t)ch*NROWS + n];
      l[ch*2+0] = AGLOAD(pp+0); c[ch*2+0] = __float_as_int(AGLOAD(pp+1));
      l[ch*2+1] = AGLOAD(pp+2); c[ch*2+1] = __float_as_int(AGLOAD(pp+3));
    }
    float mm = l[0];
#pragma unroll
    for (int i = 1; i < 16; ++i) mm = fmaxf(mm, l[i]);

    int bb = n >> 8, hw = n & 255;
    float zr[32], zn = 0.f;
#pragma unroll
    for (int cc = 0; cc < CDIM; ++cc) {
      zr[cc] = z[(size_t)bb*8192 + cc*256 + hw];
      zn = fmaf(zr[cc], zr[cc], zn);
    }
    float bd = 3.0e38f; int bc = 0x7fffffff;
#pragma unroll
    for (int i = 0; i < 16; ++i) {
      if (l[i] > mm - MARGIN) {
        int code = c[i];
        const float4* er4 = (const float4*)(emb + (size_t)code*CDIM);
        float dot = 0.f;
#pragma unroll
        for (int q = 0; q < 8; ++q) {
          float4 e4 = er4[q];
          dot = fmaf(zr[q*4+0], e4.x, dot);
          dot = fmaf(zr[q*4+1], e4.y, dot);
          dot = fmaf(zr[q*4+2], e4.z, dot);
          dot = fmaf(zr[q*4+3], e4.w, dot);
        }
        float d = (zn + enorm[code]) - 2.f*dot;   // exact fp32 distance
        if (d < bd || (d == bd && code < bc)) { bd = d; bc = code; }
      }
    }
    out[OUT_IDX + n] = (float)bc;

    const float* er = emb + (size_t)bc*CDIM;
    float msel = 0.f;
#pragma unroll
    for (int cc = 0; cc < CDIM; ++cc) {
      float zq = er[cc];
      float df = zq - zr[cc];
      msel = fmaf(df, df, msel);
      out[(size_t)bb*8192 + cc*256 + hw] = zr[cc] + (zq - zr[cc]);
    }

    float s = 0.f;
#pragma unroll
    for (int i = 0; i < 16; ++i) s += __expf(l[i] - mm);   // max term = 1 -> NaN-proof
    float lse = mm + __logf(s);
    float plp = 0.f;
#pragma unroll
    for (int i = 0; i < 16; ++i) {
      float u = l[i] - lse;
      float p = __expf(u);
      plp = fmaf(p, u, plp);
      if (p > 1e-12f) atomicAdd(&ws[WS_AVGP + c[i]], p);
    }
#pragma unroll
    for (int off = 1; off < 32; off <<= 1) {
      msel += __shfl_xor(msel, off);
      plp  += __shfl_xor(plp, off);
    }
    if (tid == 0) { atomicAdd(&ws[WS_MSE], msel); atomicAdd(&ws[WS_PLP], plp); }
  }

  // ---- gate 2: last rowgroup does finalize ----
  __threadfence();
  __syncthreads();
  if (tid == 0)
    flag_s = (atomicAdd((int*)ws + WS_GCNT, 1) == NRG - 1);
  __syncthreads();
  if (!flag_s) return;
  __threadfence();

  float h = 0.f;
  for (int k = tid; k < KCODES; k += 256) {
    float ap = AGLOAD(&ws[WS_AVGP + k]) * (1.f/8192.f);
    h += ap * __logf(ap + 1e-5f);
  }
  red[tid] = h;
  __syncthreads();
  for (int st = 128; st > 0; st >>= 1) {
    if (tid < st) red[tid] += red[tid + st];
    __syncthreads();
  }
  if (tid == 0) {
    float mse        = AGLOAD(&ws[WS_MSE]) * (1.f/(8192.f*32.f));
    float sample_ent = -AGLOAD(&ws[WS_PLP]) * (1.f/8192.f);
    out[OUT_LOSS] = 1.25f*mse + 0.1f*(sample_ent + red[0]);
  }
}

extern "C" void kernel_launch(void* const* d_in, const int* in_sizes, int n_in,
                              void* d_out, int out_size, void* d_ws, size_t ws_size,
                              hipStream_t stream) {
  (void)in_sizes; (void)n_in; (void)out_size; (void)ws_size;
  const float* z   = (const float*)d_in[0];
  const float* emb = (const float*)d_in[1];
  float* out = (float*)d_out;
  float* ws  = (float*)d_ws;

  prep_kernel<<<96, 256, 0, stream>>>(z, emb, ws);
  gemm_pass  <<<dim3(NRG, KSPLIT), 256, 0, stream>>>(z, emb, ws, out);
}

// Round 14
// 180.381 us; speedup vs baseline: 1.5651x; 1.5651x over previous
//
#include <hip/hip_runtime.h>

#define KCODES 16384
#define CDIM   32
#define NROWS  8192
#define KSPLIT 8                  // chunks (blockIdx.y)
#define CHUNK  (KCODES/KSPLIT)    // 2048
#define WCODES (CHUNK/4)          // 512 codes per wave
#define NT     (WCODES/16)        // 32 MFMA code-tiles per wave
#define MARGIN 4.0f               // covers f16 mfma error (~0.8) + 2x tag noise (0.4)
#define NCB    (NROWS/64)         // 128 combine blocks

typedef _Float16 half8 __attribute__((ext_vector_type(8)));
typedef float    floatx4 __attribute__((ext_vector_type(4)));

// workspace layout (float indices)
#define WS_MSE   0
#define WS_PLP   1
#define WS_GCNT  2                       // int: combine->finalize gate
#define WS_AVGP  16                      // [16384]
#define WS_ENORM (16 + KCODES)           // [16384] fp32, exact
#define WS_ZNORM (16 + 2*KCODES)         // [8192]  fp32
#define WS_PART  (16 + 2*KCODES + NROWS) // float4[KSPLIT][NROWS]
#define WS_E16   (WS_PART + 4*KSPLIT*NROWS)      // f16[16384][32]
#define WS_Z16   (WS_E16 + KCODES*16)            // f16[8192][32]

// output layout (floats): z_q [0, N*C), loss [N*C], idx [N*C+1, ...)
#define OUT_LOSS (NROWS*CDIM)
#define OUT_IDX  (NROWS*CDIM + 1)

#define AGLOAD(p) __hip_atomic_load((p), __ATOMIC_RELAXED, __HIP_MEMORY_SCOPE_AGENT)

// ---------------------------------------------------------------------------
// prep (R12-exact): blocks [0,64): e-rows (enorm + f16 + zero avg_probs);
// blocks [64,96): z-rows (znorm + f16); block 64 zeroes scalars (incl GCNT).
// ---------------------------------------------------------------------------
__global__ __launch_bounds__(256) void prep_kernel(const float* __restrict__ z,
                                                   const float* __restrict__ emb,
                                                   float* __restrict__ ws) {
  const int tid = threadIdx.x;
  if (blockIdx.x < 64) {
    int k = blockIdx.x * 256 + tid;
    const float4* p = (const float4*)(emb + (size_t)k * CDIM);
    _Float16* e16 = (_Float16*)(ws + WS_E16);
    float s = 0.f;
    half8 h[4];
#pragma unroll
    for (int i = 0; i < 8; ++i) {
      float4 v = p[i];
      s += v.x*v.x + v.y*v.y + v.z*v.z + v.w*v.w;
      h[i>>1][(i&1)*4+0] = (_Float16)v.x;
      h[i>>1][(i&1)*4+1] = (_Float16)v.y;
      h[i>>1][(i&1)*4+2] = (_Float16)v.z;
      h[i>>1][(i&1)*4+3] = (_Float16)v.w;
    }
    ws[WS_ENORM + k] = s;
    ws[WS_AVGP + k]  = 0.f;
    half8* dst = (half8*)(e16 + (size_t)k*32);
#pragma unroll
    for (int i = 0; i < 4; ++i) dst[i] = h[i];
  } else {
    int b = blockIdx.x - 64;
    int n = b*256 + tid;
    if (b == 0 && tid < 16) ws[tid] = 0.f;
    _Float16* z16 = (_Float16*)(ws + WS_Z16);
    float s = 0.f;
    half8 h[4];
#pragma unroll
    for (int c = 0; c < CDIM; ++c) {
      float v = z[(size_t)b*8192 + c*256 + tid];
      s = fmaf(v, v, s);
      h[c>>3][c&7] = (_Float16)v;
    }
    ws[WS_ZNORM + n] = s;
    half8* dst = (half8*)(z16 + (size_t)n*32);
#pragma unroll
    for (int i = 0; i < 4; ++i) dst[i] = h[i];
  }
}

// ---------------------------------------------------------------------------
// gemm_pass (R12-exact — proven 47.7 us; do not touch): block = (32 rows,
// chunk of 2048 codes); 4 waves x 512 codes; per wave 2 row-tiles x 32 tiles
// of v_mfma_f32_16x16x32_f16, bias in C operand, 12-bit code-tagged top-2,
// butterfly merge, 1 KB LDS.
// ---------------------------------------------------------------------------
__global__ __launch_bounds__(256) void gemm_pass(const float* __restrict__ ws_ro,
                                                 float* __restrict__ ws) {
  __shared__ float2 wdump[4][32];       // [wave][row] top-2 tagged floats

  const int tid  = threadIdx.x;
  const int wv   = tid >> 6;
  const int lane = tid & 63;
  const int nn   = lane & 15;
  const int quad = lane >> 4;
  const int n0   = blockIdx.x * 32;
  const int kb   = blockIdx.y * CHUNK + wv * WCODES;

  const half8* z16v = (const half8*)(ws_ro + WS_Z16);
  const half8* e16v = (const half8*)(ws_ro + WS_E16);
  const float* enorm = ws_ro + WS_ENORM;
  const float* znorm = ws_ro + WS_ZNORM;
  float4* part = (float4*)(ws + WS_PART);

  half8 a0 = z16v[(size_t)(n0 + nn)*4 + quad];
  half8 a1 = z16v[(size_t)(n0 + 16 + nn)*4 + quad];

  float nzn2[8];                        // -0.5*znorm[row]
#pragma unroll
  for (int i = 0; i < 8; ++i)
    nzn2[i] = -0.5f * znorm[n0 + (i>>2)*16 + quad*4 + (i&3)];

  float t1l[8], t2l[8];
#pragma unroll
  for (int i = 0; i < 8; ++i) { t1l[i] = -3.0e38f; t2l[i] = -3.0e38f; }

  const int tagbase = wv*WCODES + nn;   // full within-chunk code of tile 0
  half8 bcur = e16v[(size_t)(kb + nn)*4 + quad];
  float en2c = 0.5f * enorm[kb + nn];

  for (int t = 0; t < NT; ++t) {
    const int tn = (t + 1 < NT) ? t + 1 : t;      // clamp: last prefetch reuses
    half8 bn   = e16v[(size_t)(kb + tn*16 + nn)*4 + quad];
    float en2n = 0.5f * enorm[kb + tn*16 + nn];

    floatx4 c0, c1;
#pragma unroll
    for (int i = 0; i < 4; ++i) { c0[i] = nzn2[i] - en2c; c1[i] = nzn2[i+4] - en2c; }

    floatx4 d0 = __builtin_amdgcn_mfma_f32_16x16x32_f16(a0, bcur, c0, 0, 0, 0);
    floatx4 d1 = __builtin_amdgcn_mfma_f32_16x16x32_f16(a1, bcur, c1, 0, 0, 0);

    const int tg = tagbase + 16*t;                // 12-bit within-chunk code
#pragma unroll
    for (int i = 0; i < 8; ++i) {
      float lp = (i < 4) ? d0[i & 3] : d1[i & 3];
      float v  = __int_as_float((__float_as_int(lp) & 0xFFFFF000) | tg);  // bfi
      t2l[i] = __builtin_amdgcn_fmed3f(v, t1l[i], t2l[i]);
      t1l[i] = fmaxf(t1l[i], v);
    }
    bcur = bn; en2c = en2n;
  }

  // butterfly top-2 merge across the 16 nn-lanes (xor 1,2,4,8 stay in-group)
#pragma unroll
  for (int i = 0; i < 8; ++i) {
    float v1 = t1l[i], v2 = t2l[i];
#pragma unroll
    for (int m = 1; m < 16; m <<= 1) {
      float o1 = __shfl_xor(v1, m);
      float o2 = __shfl_xor(v2, m);
      float mn = fminf(v1, o1);
      v1 = fmaxf(v1, o1);
      v2 = fmaxf(mn, fmaxf(v2, o2));
    }
    if (nn == 0) wdump[wv][(i>>2)*16 + quad*4 + (i&3)] = make_float2(v1, v2);
  }
  __syncthreads();

  // merge 4 waves per row, unpack tags -> (l, code), write part
  if (tid < 32) {
    float v1 = -3.0e38f, v2 = -3.0e38f;
#pragma unroll
    for (int w = 0; w < 4; ++w) {
      float2 p = wdump[w][tid];
      float mn = fminf(v1, p.x);
      v1 = fmaxf(v1, p.x);
      v2 = fmaxf(mn, fmaxf(v2, p.y));
    }
    int b1 = __float_as_int(v1), b2 = __float_as_int(v2);
    int c1i = blockIdx.y*CHUNK + (b1 & 0xFFF);
    int c2i = blockIdx.y*CHUNK + (b2 & 0xFFF);
    float l1 = 200.f * __int_as_float(b1 & 0xFFFFF000);
    float l2 = 200.f * __int_as_float(b2 & 0xFFFFF000);
    part[(size_t)blockIdx.y*NROWS + n0 + tid] =
        make_float4(l1, __int_as_float(c1i), l2, __int_as_float(c2i));
  }
}

// ---------------------------------------------------------------------------
// combine (+fused zq + finalize): R12 combine, then last-arriving block (gate
// counter, R13-proven-correct mechanism) computes the entropy/loss scalar.
// 128 blocks -> 128 fences total (16x fewer than R13's 2048-block gate).
// ---------------------------------------------------------------------------
__global__ __launch_bounds__(64) void combine_kernel(const float* __restrict__ z,
                                                     const float* __restrict__ emb,
                                                     float* __restrict__ ws,
                                                     float* __restrict__ out) {
  __shared__ float red[64];
  __shared__ int   flag_s;
  const float4* part = (const float4*)(ws + WS_PART);
  int n = blockIdx.x*64 + threadIdx.x;

  float l[16]; int c[16];
#pragma unroll
  for (int ch = 0; ch < KSPLIT; ++ch) {
    float4 v = part[(size_t)ch*NROWS + n];
    l[ch*2+0] = v.x; c[ch*2+0] = __float_as_int(v.y);
    l[ch*2+1] = v.z; c[ch*2+1] = __float_as_int(v.w);
  }
  float mm = l[0];
#pragma unroll
  for (int i = 1; i < 16; ++i) mm = fmaxf(mm, l[i]);

  int bb = n >> 8, hw = n & 255;
  float zr[32];
  float zn = 0.f;
#pragma unroll
  for (int cc = 0; cc < CDIM; ++cc) {
    zr[cc] = z[(size_t)bb*8192 + cc*256 + hw];
    zn = fmaf(zr[cc], zr[cc], zn);
  }
  float bd = 3.0e38f; int bc = 0x7fffffff;
#pragma unroll
  for (int i = 0; i < 16; ++i) {
    if (l[i] > mm - MARGIN) {
      int code = c[i];
      const float4* er4 = (const float4*)(emb + (size_t)code*CDIM);
      float dot = 0.f;
#pragma unroll
      for (int q = 0; q < 8; ++q) {
        float4 e4 = er4[q];
        dot = fmaf(zr[q*4+0], e4.x, dot);
        dot = fmaf(zr[q*4+1], e4.y, dot);
        dot = fmaf(zr[q*4+2], e4.z, dot);
        dot = fmaf(zr[q*4+3], e4.w, dot);
      }
      float d = (zn + ws[WS_ENORM + code]) - 2.f*dot;   // exact fp32 distance
      if (d < bd || (d == bd && code < bc)) { bd = d; bc = code; }
    }
  }
  out[OUT_IDX + n] = (float)bc;

  // fused zq: straight-through output + MSE (coalesced per-c stores)
  const float* er = emb + (size_t)bc*CDIM;
  float msel = 0.f;
#pragma unroll
  for (int cc = 0; cc < CDIM; ++cc) {
    float zq = er[cc];
    float df = zq - zr[cc];
    msel = fmaf(df, df, msel);
    out[(size_t)bb*8192 + cc*256 + hw] = zr[cc] + (zq - zr[cc]);
  }
  for (int off = 1; off < 64; off <<= 1) msel += __shfl_xor(msel, off);
  if (threadIdx.x == 0) atomicAdd(&ws[WS_MSE], msel);

  // loss softmax from approx pairs (max term = exp(0)=1 -> NaN-proof)
  float s = 0.f;
#pragma unroll
  for (int i = 0; i < 16; ++i) s += __expf(l[i] - mm);
  float lse = mm + __logf(s);

  float plp = 0.f;
#pragma unroll
  for (int i = 0; i < 16; ++i) {
    float u = l[i] - lse;
    float p = __expf(u);
    plp = fmaf(p, u, plp);
    if (p > 1e-12f) atomicAdd(&ws[WS_AVGP + c[i]], p);
  }
  for (int off = 1; off < 64; off <<= 1) plp += __shfl_xor(plp, off);
  if (threadIdx.x == 0) atomicAdd(&ws[WS_PLP], plp);

  // ---- gate: last-arriving block computes the loss scalar ----
  __threadfence();
  __syncthreads();
  if (threadIdx.x == 0)
    flag_s = (atomicAdd((int*)ws + WS_GCNT, 1) == NCB - 1);
  __syncthreads();
  if (!flag_s) return;
  __threadfence();

  float h = 0.f;
  for (int k = threadIdx.x; k < KCODES; k += 64) {
    float ap = AGLOAD(&ws[WS_AVGP + k]) * (1.f/8192.f);
    h += ap * __logf(ap + 1e-5f);
  }
  red[threadIdx.x] = h;
  __syncthreads();
  for (int st = 32; st > 0; st >>= 1) {
    if (threadIdx.x < st) red[threadIdx.x] += red[threadIdx.x + st];
    __syncthreads();
  }
  if (threadIdx.x == 0) {
    float mse        = AGLOAD(&ws[WS_MSE]) * (1.f/(8192.f*32.f));
    float sample_ent = -AGLOAD(&ws[WS_PLP]) * (1.f/8192.f);
    out[OUT_LOSS] = 1.25f*mse + 0.1f*(sample_ent + red[0]);
  }
}

extern "C" void kernel_launch(void* const* d_in, const int* in_sizes, int n_in,
                              void* d_out, int out_size, void* d_ws, size_t ws_size,
                              hipStream_t stream) {
  (void)in_sizes; (void)n_in; (void)out_size; (void)ws_size;
  const float* z   = (const float*)d_in[0];
  const float* emb = (const float*)d_in[1];
  float* out = (float*)d_out;
  float* ws  = (float*)d_ws;

  prep_kernel   <<<96, 256, 0, stream>>>(z, emb, ws);
  gemm_pass     <<<dim3(NROWS/32, KSPLIT), 256, 0, stream>>>(ws, ws);
  combine_kernel<<<NROWS/64, 64, 0, stream>>>(z, emb, ws, out);
}

// Round 15
// 179.939 us; speedup vs baseline: 1.5689x; 1.0025x over previous
//
#include <hip/hip_runtime.h>

#define KCODES 16384
#define CDIM   32
#define NROWS  8192
#define KSPLIT 8                  // chunks (blockIdx.y)
#define CHUNK  (KCODES/KSPLIT)    // 2048
#define WCODES (CHUNK/4)          // 512 codes per wave
#define NT     (WCODES/16)        // 32 MFMA code-tiles per wave
#define MARGIN 4.0f               // >>(f16 mfma err ~0.8 + tag noise ~0.2) in l-units
#define NCB    (NROWS/64)         // 128 combine blocks

typedef _Float16 half8 __attribute__((ext_vector_type(8)));
typedef float    floatx4 __attribute__((ext_vector_type(4)));

// workspace layout (float indices)
#define WS_MSE   0
#define WS_PLP   1
#define WS_GCNT  2                       // int: combine->finalize gate
#define WS_AVGP  16                      // [16384]
#define WS_ENORM (16 + KCODES)           // [16384] fp32, exact
#define WS_ZNORM (16 + 2*KCODES)         // [8192]  fp32
#define WS_PART  (16 + 2*KCODES + NROWS) // float4[KSPLIT][NROWS]
#define WS_E16   (WS_PART + 4*KSPLIT*NROWS)      // f16[16384][32]
#define WS_Z16   (WS_E16 + KCODES*16)            // f16[8192][32]

// output layout (floats): z_q [0, N*C), loss [N*C], idx [N*C+1, ...)
#define OUT_LOSS (NROWS*CDIM)
#define OUT_IDX  (NROWS*CDIM + 1)

#define AGLOAD(p) __hip_atomic_load((p), __ATOMIC_RELAXED, __HIP_MEMORY_SCOPE_AGENT)

// ---------------------------------------------------------------------------
// prep (R12-exact): blocks [0,64): e-rows (enorm + f16 + zero avg_probs);
// blocks [64,96): z-rows (znorm + f16); block 64 zeroes scalars (incl GCNT).
// ---------------------------------------------------------------------------
__global__ __launch_bounds__(256) void prep_kernel(const float* __restrict__ z,
                                                   const float* __restrict__ emb,
                                                   float* __restrict__ ws) {
  const int tid = threadIdx.x;
  if (blockIdx.x < 64) {
    int k = blockIdx.x * 256 + tid;
    const float4* p = (const float4*)(emb + (size_t)k * CDIM);
    _Float16* e16 = (_Float16*)(ws + WS_E16);
    float s = 0.f;
    half8 h[4];
#pragma unroll
    for (int i = 0; i < 8; ++i) {
      float4 v = p[i];
      s += v.x*v.x + v.y*v.y + v.z*v.z + v.w*v.w;
      h[i>>1][(i&1)*4+0] = (_Float16)v.x;
      h[i>>1][(i&1)*4+1] = (_Float16)v.y;
      h[i>>1][(i&1)*4+2] = (_Float16)v.z;
      h[i>>1][(i&1)*4+3] = (_Float16)v.w;
    }
    ws[WS_ENORM + k] = s;
    ws[WS_AVGP + k]  = 0.f;
    half8* dst = (half8*)(e16 + (size_t)k*32);
#pragma unroll
    for (int i = 0; i < 4; ++i) dst[i] = h[i];
  } else {
    int b = blockIdx.x - 64;
    int n = b*256 + tid;
    if (b == 0 && tid < 16) ws[tid] = 0.f;
    _Float16* z16 = (_Float16*)(ws + WS_Z16);
    float s = 0.f;
    half8 h[4];
#pragma unroll
    for (int c = 0; c < CDIM; ++c) {
      float v = z[(size_t)b*8192 + c*256 + tid];
      s = fmaf(v, v, s);
      h[c>>3][c&7] = (_Float16)v;
    }
    ws[WS_ZNORM + n] = s;
    half8* dst = (half8*)(z16 + (size_t)n*32);
#pragma unroll
    for (int i = 0; i < 4; ++i) dst[i] = h[i];
  }
}

// ---------------------------------------------------------------------------
// gemm_pass (R12 structure; ONE arithmetic change): per-row bias -zn2 is
// dropped from the hot loop (argmax per row is invariant to a row-constant),
// so the MFMA C operand is just the broadcast -en2/2 (1 mul vs 1 mul + 8
// subs per tile, ~12% of the 83%-busy VALU issue). -0.5*znorm applied once
// at unpack. Side benefit: |lp| drops ~16 -> ~2, so 12-bit tag truncation
// noise drops 1.6 -> 0.2 l-units.
// ---------------------------------------------------------------------------
__global__ __launch_bounds__(256) void gemm_pass(const float* __restrict__ ws_ro,
                                                 float* __restrict__ ws) {
  __shared__ float2 wdump[4][32];       // [wave][row] top-2 tagged floats

  const int tid  = threadIdx.x;
  const int wv   = tid >> 6;
  const int lane = tid & 63;
  const int nn   = lane & 15;
  const int quad = lane >> 4;
  const int n0   = blockIdx.x * 32;
  const int kb   = blockIdx.y * CHUNK + wv * WCODES;

  const half8* z16v = (const half8*)(ws_ro + WS_Z16);
  const half8* e16v = (const half8*)(ws_ro + WS_E16);
  const float* enorm = ws_ro + WS_ENORM;
  const float* znorm = ws_ro + WS_ZNORM;
  float4* part = (float4*)(ws + WS_PART);

  half8 a0 = z16v[(size_t)(n0 + nn)*4 + quad];
  half8 a1 = z16v[(size_t)(n0 + 16 + nn)*4 + quad];

  float t1l[8], t2l[8];
#pragma unroll
  for (int i = 0; i < 8; ++i) { t1l[i] = -3.0e38f; t2l[i] = -3.0e38f; }

  const int tagbase = wv*WCODES + nn;   // full within-chunk code of tile 0
  half8 bcur = e16v[(size_t)(kb + nn)*4 + quad];
  float enc  = enorm[kb + nn];

  for (int t = 0; t < NT; ++t) {
    const int tn = (t + 1 < NT) ? t + 1 : t;      // clamp: last prefetch reuses
    half8 bn  = e16v[(size_t)(kb + tn*16 + nn)*4 + quad];
    float enn = enorm[kb + tn*16 + nn];

    float neh = -0.5f * enc;                      // broadcast bias: D = dot - en2
    floatx4 cb;
#pragma unroll
    for (int i = 0; i < 4; ++i) cb[i] = neh;

    floatx4 d0 = __builtin_amdgcn_mfma_f32_16x16x32_f16(a0, bcur, cb, 0, 0, 0);
    floatx4 d1 = __builtin_amdgcn_mfma_f32_16x16x32_f16(a1, bcur, cb, 0, 0, 0);

    const int tg = tagbase + 16*t;                // 12-bit within-chunk code
#pragma unroll
    for (int i = 0; i < 8; ++i) {
      float lp = (i < 4) ? d0[i & 3] : d1[i & 3];
      float v  = __int_as_float((__float_as_int(lp) & 0xFFFFF000) | tg);  // bfi
      t2l[i] = __builtin_amdgcn_fmed3f(v, t1l[i], t2l[i]);
      t1l[i] = fmaxf(t1l[i], v);
    }
    bcur = bn; enc = enn;
  }

  // butterfly top-2 merge across the 16 nn-lanes (same-row exchanges only)
#pragma unroll
  for (int i = 0; i < 8; ++i) {
    float v1 = t1l[i], v2 = t2l[i];
#pragma unroll
    for (int m = 1; m < 16; m <<= 1) {
      float o1 = __shfl_xor(v1, m);
      float o2 = __shfl_xor(v2, m);
      float mn = fminf(v1, o1);
      v1 = fmaxf(v1, o1);
      v2 = fmaxf(mn, fmaxf(v2, o2));
    }
    if (nn == 0) wdump[wv][(i>>2)*16 + quad*4 + (i&3)] = make_float2(v1, v2);
  }
  __syncthreads();

  // merge 4 waves per row, unpack tags -> (l, code) applying -0.5*znorm here
  if (tid < 32) {
    float v1 = -3.0e38f, v2 = -3.0e38f;
#pragma unroll
    for (int w = 0; w < 4; ++w) {
      float2 p = wdump[w][tid];
      float mn = fminf(v1, p.x);
      v1 = fmaxf(v1, p.x);
      v2 = fmaxf(mn, fmaxf(v2, p.y));
    }
    float znh = 0.5f * znorm[n0 + tid];
    int b1 = __float_as_int(v1), b2 = __float_as_int(v2);
    int c1i = blockIdx.y*CHUNK + (b1 & 0xFFF);
    int c2i = blockIdx.y*CHUNK + (b2 & 0xFFF);
    float l1 = 200.f * (__int_as_float(b1 & 0xFFFFF000) - znh);
    float l2 = 200.f * (__int_as_float(b2 & 0xFFFFF000) - znh);
    part[(size_t)blockIdx.y*NROWS + n0 + tid] =
        make_float4(l1, __int_as_float(c1i), l2, __int_as_float(c2i));
  }
}

// ---------------------------------------------------------------------------
// combine (+fused zq + finalize): R14 minus the __threadfence()s. Everything
// the finalize tail reads (AVGP/MSE/PLP) is written ONLY by device-scope
// atomicAdd (coherent point, m20) and read via agent-scope atomic loads —
// no L2 writeback needed. Gate ordering = s_waitcnt vmcnt(0) (drain this
// wave's outstanding atomics) + compiler barriers. R14's threadfence cost:
// buffer_wbl2 full-L2 writeback per block -> combine 84 us.
// ---------------------------------------------------------------------------
__global__ __launch_bounds__(64) void combine_kernel(const float* __restrict__ z,
                                                     const float* __restrict__ emb,
                                                     float* __restrict__ ws,
                                                     float* __restrict__ out) {
  __shared__ float red[64];
  __shared__ int   flag_s;
  const float4* part = (const float4*)(ws + WS_PART);
  int n = blockIdx.x*64 + threadIdx.x;

  float l[16]; int c[16];
#pragma unroll
  for (int ch = 0; ch < KSPLIT; ++ch) {
    float4 v = part[(size_t)ch*NROWS + n];
    l[ch*2+0] = v.x; c[ch*2+0] = __float_as_int(v.y);
    l[ch*2+1] = v.z; c[ch*2+1] = __float_as_int(v.w);
  }
  float mm = l[0];
#pragma unroll
  for (int i = 1; i < 16; ++i) mm = fmaxf(mm, l[i]);

  int bb = n >> 8, hw = n & 255;
  float zr[32];
  float zn = 0.f;
#pragma unroll
  for (int cc = 0; cc < CDIM; ++cc) {
    zr[cc] = z[(size_t)bb*8192 + cc*256 + hw];
    zn = fmaf(zr[cc], zr[cc], zn);
  }
  float bd = 3.0e38f; int bc = 0x7fffffff;
#pragma unroll
  for (int i = 0; i < 16; ++i) {
    if (l[i] > mm - MARGIN) {
      int code = c[i];
      const float4* er4 = (const float4*)(emb + (size_t)code*CDIM);
      float dot = 0.f;
#pragma unroll
      for (int q = 0; q < 8; ++q) {
        float4 e4 = er4[q];
        dot = fmaf(zr[q*4+0], e4.x, dot);
        dot = fmaf(zr[q*4+1], e4.y, dot);
        dot = fmaf(zr[q*4+2], e4.z, dot);
        dot = fmaf(zr[q*4+3], e4.w, dot);
      }
      float d = (zn + ws[WS_ENORM + code]) - 2.f*dot;   // exact fp32 distance
      if (d < bd || (d == bd && code < bc)) { bd = d; bc = code; }
    }
  }
  out[OUT_IDX + n] = (float)bc;

  // fused zq: straight-through output + MSE (coalesced per-c stores)
  const float* er = emb + (size_t)bc*CDIM;
  float msel = 0.f;
#pragma unroll
  for (int cc = 0; cc < CDIM; ++cc) {
    float zq = er[cc];
    float df = zq - zr[cc];
    msel = fmaf(df, df, msel);
    out[(size_t)bb*8192 + cc*256 + hw] = zr[cc] + (zq - zr[cc]);
  }
  for (int off = 1; off < 64; off <<= 1) msel += __shfl_xor(msel, off);
  if (threadIdx.x == 0) atomicAdd(&ws[WS_MSE], msel);

  // loss softmax from approx pairs (max term = exp(0)=1 -> NaN-proof)
  float s = 0.f;
#pragma unroll
  for (int i = 0; i < 16; ++i) s += __expf(l[i] - mm);
  float lse = mm + __logf(s);

  float plp = 0.f;
#pragma unroll
  for (int i = 0; i < 16; ++i) {
    float u = l[i] - lse;
    float p = __expf(u);
    plp = fmaf(p, u, plp);
    if (p > 1e-12f) atomicAdd(&ws[WS_AVGP + c[i]], p);
  }
  for (int off = 1; off < 64; off <<= 1) plp += __shfl_xor(plp, off);
  if (threadIdx.x == 0) atomicAdd(&ws[WS_PLP], plp);

  // ---- gate: last-arriving block computes the loss scalar ----
  // NO threadfence: gate-protected data is all atomics (coherent point).
  __syncthreads();
  if (threadIdx.x == 0) {
    asm volatile("s_waitcnt vmcnt(0)" ::: "memory");  // prior atomics complete
    flag_s = (atomicAdd((int*)ws + WS_GCNT, 1) == NCB - 1);
  }
  __syncthreads();
  if (!flag_s) return;
  asm volatile("" ::: "memory");        // no hoisting of reads above the gate

  float h = 0.f;
  for (int k = threadIdx.x; k < KCODES; k += 64) {
    float ap = AGLOAD(&ws[WS_AVGP + k]) * (1.f/8192.f);
    h += ap * __logf(ap + 1e-5f);
  }
  red[threadIdx.x] = h;
  __syncthreads();
  for (int st = 32; st > 0; st >>= 1) {
    if (threadIdx.x < st) red[threadIdx.x] += red[threadIdx.x + st];
    __syncthreads();
  }
  if (threadIdx.x == 0) {
    float mse        = AGLOAD(&ws[WS_MSE]) * (1.f/(8192.f*32.f));
    float sample_ent = -AGLOAD(&ws[WS_PLP]) * (1.f/8192.f);
    out[OUT_LOSS] = 1.25f*mse + 0.1f*(sample_ent + red[0]);
  }
}

extern "C" void kernel_launch(void* const* d_in, const int* in_sizes, int n_in,
                              void* d_out, int out_size, void* d_ws, size_t ws_size,
                              hipStream_t stream) {
  (void)in_sizes; (void)n_in; (void)out_size; (void)ws_size;
  const float* z   = (const float*)d_in[0];
  const float* emb = (const float*)d_in[1];
  float* out = (float*)d_out;
  float* ws  = (float*)d_ws;

  prep_kernel   <<<96, 256, 0, stream>>>(z, emb, ws);
  gemm_pass     <<<dim3(NROWS/32, KSPLIT), 256, 0, stream>>>(ws, ws);
  combine_kernel<<<NROWS/64, 64, 0, stream>>>(z, emb, ws, out);
}

// Round 16
// 128.877 us; speedup vs baseline: 2.1906x; 1.3962x over previous
//
#include <hip/hip_runtime.h>

#define KCODES 16384
#define CDIM   32
#define NROWS  8192
#define KSPLIT 8                  // chunks (blockIdx.y)
#define CHUNK  (KCODES/KSPLIT)    // 2048
#define WCODES (CHUNK/4)          // 512 codes per wave
#define NT     (WCODES/16)        // 32 MFMA code-tiles per wave
#define MARGIN 4.0f               // >>(f16 mfma err ~0.8 + tag noise ~0.2) in l-units

typedef _Float16 half8 __attribute__((ext_vector_type(8)));
typedef float    floatx4 __attribute__((ext_vector_type(4)));

// workspace layout (float indices)
#define WS_MSE   0
#define WS_PLP   1
#define WS_AVGP  16                      // [16384]
#define WS_ENORM (16 + KCODES)           // [16384] fp32, exact
#define WS_ZNORM (16 + 2*KCODES)         // [8192]  fp32
#define WS_PART  (16 + 2*KCODES + NROWS) // float4[KSPLIT][NROWS]
#define WS_E16   (WS_PART + 4*KSPLIT*NROWS)      // f16[16384][32]
#define WS_Z16   (WS_E16 + KCODES*16)            // f16[8192][32]

// output layout (floats): z_q [0, N*C), loss [N*C], idx [N*C+1, ...)
#define OUT_LOSS (NROWS*CDIM)
#define OUT_IDX  (NROWS*CDIM + 1)

// ---------------------------------------------------------------------------
// prep (R12-exact): blocks [0,64): e-rows (enorm + f16 + zero avg_probs);
// blocks [64,96): z-rows (znorm + f16); block 64 zeroes scalars.
// ---------------------------------------------------------------------------
__global__ __launch_bounds__(256) void prep_kernel(const float* __restrict__ z,
                                                   const float* __restrict__ emb,
                                                   float* __restrict__ ws) {
  const int tid = threadIdx.x;
  if (blockIdx.x < 64) {
    int k = blockIdx.x * 256 + tid;
    const float4* p = (const float4*)(emb + (size_t)k * CDIM);
    _Float16* e16 = (_Float16*)(ws + WS_E16);
    float s = 0.f;
    half8 h[4];
#pragma unroll
    for (int i = 0; i < 8; ++i) {
      float4 v = p[i];
      s += v.x*v.x + v.y*v.y + v.z*v.z + v.w*v.w;
      h[i>>1][(i&1)*4+0] = (_Float16)v.x;
      h[i>>1][(i&1)*4+1] = (_Float16)v.y;
      h[i>>1][(i&1)*4+2] = (_Float16)v.z;
      h[i>>1][(i&1)*4+3] = (_Float16)v.w;
    }
    ws[WS_ENORM + k] = s;
    ws[WS_AVGP + k]  = 0.f;
    half8* dst = (half8*)(e16 + (size_t)k*32);
#pragma unroll
    for (int i = 0; i < 4; ++i) dst[i] = h[i];
  } else {
    int b = blockIdx.x - 64;
    int n = b*256 + tid;
    if (b == 0 && tid < 16) ws[tid] = 0.f;
    _Float16* z16 = (_Float16*)(ws + WS_Z16);
    float s = 0.f;
    half8 h[4];
#pragma unroll
    for (int c = 0; c < CDIM; ++c) {
      float v = z[(size_t)b*8192 + c*256 + tid];
      s = fmaf(v, v, s);
      h[c>>3][c&7] = (_Float16)v;
    }
    ws[WS_ZNORM + n] = s;
    half8* dst = (half8*)(z16 + (size_t)n*32);
#pragma unroll
    for (int i = 0; i < 4; ++i) dst[i] = h[i];
  }
}

// ---------------------------------------------------------------------------
// gemm_pass (R15-exact): broadcast -en2/2 bias in the MFMA C operand; the
// row-constant -zn2 is applied once at unpack (argmax-invariant). 12-bit
// code-tagged top-2 + butterfly merge, 1 KB LDS, no K-loop barriers.
// ---------------------------------------------------------------------------
__global__ __launch_bounds__(256) void gemm_pass(const float* __restrict__ ws_ro,
                                                 float* __restrict__ ws) {
  __shared__ float2 wdump[4][32];       // [wave][row] top-2 tagged floats

  const int tid  = threadIdx.x;
  const int wv   = tid >> 6;
  const int lane = tid & 63;
  const int nn   = lane & 15;
  const int quad = lane >> 4;
  const int n0   = blockIdx.x * 32;
  const int kb   = blockIdx.y * CHUNK + wv * WCODES;

  const half8* z16v = (const half8*)(ws_ro + WS_Z16);
  const half8* e16v = (const half8*)(ws_ro + WS_E16);
  const float* enorm = ws_ro + WS_ENORM;
  const float* znorm = ws_ro + WS_ZNORM;
  float4* part = (float4*)(ws + WS_PART);

  half8 a0 = z16v[(size_t)(n0 + nn)*4 + quad];
  half8 a1 = z16v[(size_t)(n0 + 16 + nn)*4 + quad];

  float t1l[8], t2l[8];
#pragma unroll
  for (int i = 0; i < 8; ++i) { t1l[i] = -3.0e38f; t2l[i] = -3.0e38f; }

  const int tagbase = wv*WCODES + nn;   // full within-chunk code of tile 0
  half8 bcur = e16v[(size_t)(kb + nn)*4 + quad];
  float enc  = enorm[kb + nn];

  for (int t = 0; t < NT; ++t) {
    const int tn = (t + 1 < NT) ? t + 1 : t;      // clamp: last prefetch reuses
    half8 bn  = e16v[(size_t)(kb + tn*16 + nn)*4 + quad];
    float enn = enorm[kb + tn*16 + nn];

    float neh = -0.5f * enc;                      // broadcast bias: D = dot - en2
    floatx4 cb;
#pragma unroll
    for (int i = 0; i < 4; ++i) cb[i] = neh;

    floatx4 d0 = __builtin_amdgcn_mfma_f32_16x16x32_f16(a0, bcur, cb, 0, 0, 0);
    floatx4 d1 = __builtin_amdgcn_mfma_f32_16x16x32_f16(a1, bcur, cb, 0, 0, 0);

    const int tg = tagbase + 16*t;                // 12-bit within-chunk code
#pragma unroll
    for (int i = 0; i < 8; ++i) {
      float lp = (i < 4) ? d0[i & 3] : d1[i & 3];
      float v  = __int_as_float((__float_as_int(lp) & 0xFFFFF000) | tg);  // bfi
      t2l[i] = __builtin_amdgcn_fmed3f(v, t1l[i], t2l[i]);
      t1l[i] = fmaxf(t1l[i], v);
    }
    bcur = bn; enc = enn;
  }

  // butterfly top-2 merge across the 16 nn-lanes (same-row exchanges only)
#pragma unroll
  for (int i = 0; i < 8; ++i) {
    float v1 = t1l[i], v2 = t2l[i];
#pragma unroll
    for (int m = 1; m < 16; m <<= 1) {
      float o1 = __shfl_xor(v1, m);
      float o2 = __shfl_xor(v2, m);
      float mn = fminf(v1, o1);
      v1 = fmaxf(v1, o1);
      v2 = fmaxf(mn, fmaxf(v2, o2));
    }
    if (nn == 0) wdump[wv][(i>>2)*16 + quad*4 + (i&3)] = make_float2(v1, v2);
  }
  __syncthreads();

  // merge 4 waves per row, unpack tags -> (l, code), apply -0.5*znorm here
  if (tid < 32) {
    float v1 = -3.0e38f, v2 = -3.0e38f;
#pragma unroll
    for (int w = 0; w < 4; ++w) {
      float2 p = wdump[w][tid];
      float mn = fminf(v1, p.x);
      v1 = fmaxf(v1, p.x);
      v2 = fmaxf(mn, fmaxf(v2, p.y));
    }
    float znh = 0.5f * znorm[n0 + tid];
    int b1 = __float_as_int(v1), b2 = __float_as_int(v2);
    int c1i = blockIdx.y*CHUNK + (b1 & 0xFFF);
    int c2i = blockIdx.y*CHUNK + (b2 & 0xFFF);
    float l1 = 200.f * (__int_as_float(b1 & 0xFFFFF000) - znh);
    float l2 = 200.f * (__int_as_float(b2 & 0xFFFFF000) - znh);
    part[(size_t)blockIdx.y*NROWS + n0 + tid] =
        make_float4(l1, __int_as_float(c1i), l2, __int_as_float(c2i));
  }
}

// ---------------------------------------------------------------------------
// combine (+fused zq) — R12-exact, NO gate/finalize tail. R15 showed the
// fused tail's 256 serialized agent-scope atomic loads cost ~50+ us; the
// dispatch-boundary finalize with plain loads is ~5 us (R1..R12 proven).
// ---------------------------------------------------------------------------
__global__ __launch_bounds__(64) void combine_kernel(const float* __restrict__ z,
                                                     const float* __restrict__ emb,
                                                     float* __restrict__ ws,
                                                     float* __restrict__ out) {
  const float4* part = (const float4*)(ws + WS_PART);
  int n = blockIdx.x*64 + threadIdx.x;

  float l[16]; int c[16];
#pragma unroll
  for (int ch = 0; ch < KSPLIT; ++ch) {
    float4 v = part[(size_t)ch*NROWS + n];
    l[ch*2+0] = v.x; c[ch*2+0] = __float_as_int(v.y);
    l[ch*2+1] = v.z; c[ch*2+1] = __float_as_int(v.w);
  }
  float mm = l[0];
#pragma unroll
  for (int i = 1; i < 16; ++i) mm = fmaxf(mm, l[i]);

  int bb = n >> 8, hw = n & 255;
  float zr[32];
  float zn = 0.f;
#pragma unroll
  for (int cc = 0; cc < CDIM; ++cc) {
    zr[cc] = z[(size_t)bb*8192 + cc*256 + hw];
    zn = fmaf(zr[cc], zr[cc], zn);
  }
  float bd = 3.0e38f; int bc = 0x7fffffff;
#pragma unroll
  for (int i = 0; i < 16; ++i) {
    if (l[i] > mm - MARGIN) {
      int code = c[i];
      const float4* er4 = (const float4*)(emb + (size_t)code*CDIM);
      float dot = 0.f;
#pragma unroll
      for (int q = 0; q < 8; ++q) {
        float4 e4 = er4[q];
        dot = fmaf(zr[q*4+0], e4.x, dot);
        dot = fmaf(zr[q*4+1], e4.y, dot);
        dot = fmaf(zr[q*4+2], e4.z, dot);
        dot = fmaf(zr[q*4+3], e4.w, dot);
      }
      float d = (zn + ws[WS_ENORM + code]) - 2.f*dot;   // exact fp32 distance
      if (d < bd || (d == bd && code < bc)) { bd = d; bc = code; }
    }
  }
  out[OUT_IDX + n] = (float)bc;

  // fused zq: straight-through output + MSE (coalesced per-c stores)
  const float* er = emb + (size_t)bc*CDIM;
  float msel = 0.f;
#pragma unroll
  for (int cc = 0; cc < CDIM; ++cc) {
    float zq = er[cc];
    float df = zq - zr[cc];
    msel = fmaf(df, df, msel);
    out[(size_t)bb*8192 + cc*256 + hw] = zr[cc] + (zq - zr[cc]);
  }
  for (int off = 1; off < 64; off <<= 1) msel += __shfl_xor(msel, off);
  if (threadIdx.x == 0) atomicAdd(&ws[WS_MSE], msel);

  // loss softmax from approx pairs (max term = exp(0)=1 -> NaN-proof)
  float s = 0.f;
#pragma unroll
  for (int i = 0; i < 16; ++i) s += __expf(l[i] - mm);
  float lse = mm + __logf(s);

  float plp = 0.f;
#pragma unroll
  for (int i = 0; i < 16; ++i) {
    float u = l[i] - lse;
    float p = __expf(u);
    plp = fmaf(p, u, plp);
    if (p > 1e-12f) atomicAdd(&ws[WS_AVGP + c[i]], p);
  }
  for (int off = 1; off < 64; off <<= 1) plp += __shfl_xor(plp, off);
  if (threadIdx.x == 0) atomicAdd(&ws[WS_PLP], plp);
}

// ---------------------------------------------------------------------------
// finalize (separate dispatch, plain loads — R12-exact): entropy + loss.
// ---------------------------------------------------------------------------
__global__ __launch_bounds__(256) void finalize_kernel(const float* __restrict__ ws,
                                                       float* __restrict__ out) {
  __shared__ float red[256];
  float h = 0.f;
  for (int k = threadIdx.x; k < KCODES; k += 256) {
    float ap = ws[WS_AVGP + k] * (1.f/8192.f);
    h += ap * __logf(ap + 1e-5f);
  }
  red[threadIdx.x] = h;
  __syncthreads();
  for (int st = 128; st > 0; st >>= 1) {
    if (threadIdx.x < st) red[threadIdx.x] += red[threadIdx.x + st];
    __syncthreads();
  }
  if (threadIdx.x == 0) {
    float mse        = ws[WS_MSE] * (1.f/(8192.f*32.f));
    float sample_ent = -ws[WS_PLP] * (1.f/8192.f);
    out[OUT_LOSS] = 1.25f*mse + 0.1f*(sample_ent + red[0]);
  }
}

extern "C" void kernel_launch(void* const* d_in, const int* in_sizes, int n_in,
                              void* d_out, int out_size, void* d_ws, size_t ws_size,
                              hipStream_t stream) {
  (void)in_sizes; (void)n_in; (void)out_size; (void)ws_size;
  const float* z   = (const float*)d_in[0];
  const float* emb = (const float*)d_in[1];
  float* out = (float*)d_out;
  float* ws  = (float*)d_ws;

  prep_kernel    <<<96, 256, 0, stream>>>(z, emb, ws);
  gemm_pass      <<<dim3(NROWS/32, KSPLIT), 256, 0, stream>>>(ws, ws);
  combine_kernel <<<NROWS/64, 64, 0, stream>>>(z, emb, ws, out);
  finalize_kernel<<<1, 256, 0, stream>>>(ws, out);
}